// Round 6
// baseline (974.413 us; speedup 1.0000x reference)
//
#include <hip/hip_runtime.h>
#include <hip/hip_cooperative_groups.h>
#include <stdint.h>

namespace cg = cooperative_groups;

#define B_SZ 32
#define C_SZ 64
#define N_SZ 65536
#define K_SZ 8192
#define JCAP 80        // per j-bucket capacity (lambda=32; deterministic inputs verified no overflow)
#define NCHUNK 16      // chunk-blocks per batch (4096 elems each)
#define NBLK (B_SZ * NCHUNK)  // 512 blocks, co-resident (2/CU)

__device__ __forceinline__ uint32_t rotl32(uint32_t v, int r) {
  return (v << r) | (v >> (32 - r));
}

// JAX Threefry-2x32, 20 rounds.
__device__ __forceinline__ void threefry2x32(uint32_t k0, uint32_t k1,
                                             uint32_t x0, uint32_t x1,
                                             uint32_t& o0, uint32_t& o1) {
  const uint32_t ks2 = k0 ^ k1 ^ 0x1BD11BDAu;
  x0 += k0; x1 += k1;
#define TF_R(r) { x0 += x1; x1 = rotl32(x1, (r)); x1 ^= x0; }
  TF_R(13) TF_R(15) TF_R(26) TF_R(6)   x0 += k1;  x1 += ks2 + 1u;
  TF_R(17) TF_R(29) TF_R(16) TF_R(24)  x0 += ks2; x1 += k0  + 2u;
  TF_R(13) TF_R(15) TF_R(26) TF_R(6)   x0 += k0;  x1 += k1  + 3u;
  TF_R(17) TF_R(29) TF_R(16) TF_R(24)  x0 += k1;  x1 += ks2 + 4u;
  TF_R(13) TF_R(15) TF_R(26) TF_R(6)   x0 += ks2; x1 += k0  + 5u;
#undef TF_R
  o0 = x0; o1 = x1;
}

__device__ __forceinline__ void subkey_for_round(int b, int round,
                                                 uint32_t& sk0, uint32_t& sk1) {
  uint32_t c0, c1;
  threefry2x32(0u, 1u, 0u, (uint32_t)b, c0, c1);
  for (int r = 0; r < round; ++r) {
    uint32_t n0, n1;
    threefry2x32(c0, c1, 0u, 0u, n0, n1);
    c0 = n0; c1 = n1;
  }
  threefry2x32(c0, c1, 0u, 1u, sk0, sk1);
}

// per-batch 256-wide exclusive scan of hist -> baseArr(257)+cur; re-zeroes hist.
__device__ void prefix_phase(int b, int t, uint32_t* __restrict__ hist,
                             uint32_t* __restrict__ baseArr,
                             uint32_t* __restrict__ cur,
                             uint32_t* __restrict__ sc) {
  const uint32_t h = hist[b * 256 + t];
  hist[b * 256 + t] = 0;
  sc[t] = h;
  __syncthreads();
  for (int off = 1; off < 256; off <<= 1) {
    const uint32_t y = (t >= off) ? sc[t - off] : 0u;
    __syncthreads();
    sc[t] += y;
    __syncthreads();
  }
  baseArr[b * 257 + t] = sc[t] - h;
  cur[b * 256 + t] = sc[t] - h;
  if (t == 255) baseArr[b * 257 + 256] = sc[255];
}

// two-level counting-rank of one top-8 bucket (n<=512); order = stable sort by
// full key. WRITE==0: S1v[rank]=pos.  WRITE==1: emit (j<<16)|q j-bucket pairs.
template <int WRITE>
__device__ void rank_bucket(int b, int u, int t,
                            const uint64_t* __restrict__ src,
                            const uint32_t* __restrict__ baseArr,
                            uint16_t* __restrict__ S1v,
                            uint32_t* __restrict__ jcnt,
                            uint32_t* __restrict__ jb,
                            uint32_t* __restrict__ sub, uint16_t* __restrict__ dg,
                            uint16_t* __restrict__ idxt, uint32_t* __restrict__ sh_h,
                            uint32_t* __restrict__ sh_c, uint32_t* __restrict__ base2) {
  const uint32_t base = baseArr[b * 257 + u];
  if (WRITE == 1 && base >= K_SZ) return;   // uniform per block
  uint32_t n = baseArr[b * 257 + u + 1] - base;
  if (n > 512u) n = 512u;
  const uint64_t* __restrict__ g = src + (size_t)b * N_SZ + base;

  sh_h[t] = 0;
  __syncthreads();
  uint64_t rec[2] = {0, 0};
#pragma unroll
  for (int w = 0; w < 2; ++w) {
    const int e = t + w * 256;
    if (e < (int)n) {
      rec[w] = g[e];
      const uint32_t key = (uint32_t)(rec[w] >> 16);
      const uint32_t d = (key >> 16) & 0xFFu;
      sub[e] = ((key & 0xFFFFu) << 16) | (uint32_t)(rec[w] & 0xFFFFull);
      dg[e] = (uint16_t)d;
      atomicAdd(&sh_h[d], 1u);
    }
  }
  __syncthreads();
  const uint32_t h = sh_h[t];
  sh_c[t] = h;
  __syncthreads();
  for (int off = 1; off < 256; off <<= 1) {
    const uint32_t y = (t >= off) ? sh_c[t - off] : 0u;
    __syncthreads();
    sh_c[t] += y;
    __syncthreads();
  }
  base2[t] = sh_c[t] - h;
  sh_h[t] = sh_c[t] - h;            // cursor
  if (t == 255) base2[256] = sh_c[255];
  __syncthreads();
#pragma unroll
  for (int w = 0; w < 2; ++w) {
    const int e = t + w * 256;
    if (e < (int)n) idxt[atomicAdd(&sh_h[dg[e]], 1u)] = (uint16_t)e;
  }
  __syncthreads();
#pragma unroll
  for (int w = 0; w < 2; ++w) {
    const int e = t + w * 256;
    if (e < (int)n) {
      const uint32_t d = dg[e], s = sub[e];
      const uint32_t lo = base2[d], hi = base2[d + 1];
      uint32_t r = 0;
      for (uint32_t i = lo; i < hi; ++i) r += (sub[idxt[i]] < s) ? 1u : 0u;
      if (WRITE == 0) {
        S1v[(size_t)b * N_SZ + base + lo + r] = (uint16_t)(rec[w] & 0xFFFFull);
      } else {
        const uint32_t q = base + lo + r;
        if (q < K_SZ) {
          const uint32_t p = (uint32_t)(rec[w] & 0xFFFFull);   // round-1 rank idx
          const uint32_t j = (uint32_t)S1v[(size_t)b * N_SZ + p];
          const uint32_t slot = atomicAdd(&jcnt[b * 256 + (j >> 8)], 1u);
          if (slot < JCAP)
            jb[((size_t)b * 256 + (j >> 8)) * JCAP + slot] = (j << 16) | q;
        }
      }
    }
  }
}

__global__ __launch_bounds__(256, 2) void fused_sort(
    uint64_t* __restrict__ BV, uint64_t* __restrict__ CV,
    uint16_t* __restrict__ S1v, uint32_t* __restrict__ hist,
    uint32_t* __restrict__ baseArr, uint32_t* __restrict__ cur,
    uint32_t* __restrict__ jcnt, uint32_t* __restrict__ jb,
    uint32_t* __restrict__ sp) {
  cg::grid_group grid = cg::this_grid();
  const int t = threadIdx.x;
  const int bid = blockIdx.x;
  const int b = bid >> 4;
  const int chunk = bid & 15;

  __shared__ uint32_t sh_sub[512];
  __shared__ uint16_t sh_dg[512];
  __shared__ uint16_t sh_idx[512];
  __shared__ uint32_t sh_h[256];
  __shared__ uint32_t sh_c[256];
  __shared__ uint32_t sh_b2[257];

  // P0: zero hist + jcnt
  {
    const int g = bid * 256 + t;
    if (g < B_SZ * 256) { hist[g] = 0; jcnt[g] = 0; }
  }
  grid.sync();

  // P1: round-1 keygen into registers + histogram
  uint64_t v[16];
  {
    uint32_t sk0, sk1;
    subkey_for_round(b, 0, sk0, sk1);
    sh_h[t] = 0; __syncthreads();
    const int base = chunk * 4096;
#pragma unroll
    for (int e = 0; e < 16; ++e) {
      const int i = base + e * 256 + t;
      uint32_t o0, o1;
      threefry2x32(sk0, sk1, 0u, (uint32_t)i, o0, o1);
      const uint32_t bits = o0 ^ o1;
      v[e] = ((uint64_t)bits << 16) | (uint64_t)i;
      atomicAdd(&sh_h[bits >> 24], 1u);
    }
    __syncthreads();
    if (sh_h[t]) atomicAdd(&hist[b * 256 + t], sh_h[t]);
  }
  grid.sync();

  // P2: prefix round 1 (+ hist re-zero for round 2)
  if (bid < B_SZ) prefix_phase(bid, t, hist, baseArr, cur, sh_c);
  __threadfence();
  grid.sync();

  // P3: scatter round 1 from registers into BV
  {
    sh_c[t] = 0; __syncthreads();
    uint32_t r[16], dgv[16];
#pragma unroll
    for (int e = 0; e < 16; ++e) {
      dgv[e] = (uint32_t)(v[e] >> 40) & 0xFFu;
      r[e] = atomicAdd(&sh_c[dgv[e]], 1u);
    }
    __syncthreads();
    if (sh_c[t]) sh_h[t] = atomicAdd(&cur[b * 256 + t], sh_c[t]);
    __syncthreads();
    uint64_t* __restrict__ dst = BV + (size_t)b * N_SZ;
#pragma unroll
    for (int e = 0; e < 16; ++e)
      dst[sh_h[dgv[e]] + r[e]] = v[e];
  }
  __threadfence();
  grid.sync();

  // P4: rank-sort all 8192 round-1 buckets (grid-stride, 16/block)
  for (int vb = bid; vb < B_SZ * 256; vb += NBLK) {
    rank_bucket<0>(vb >> 8, vb & 255, t, BV, baseArr, S1v, nullptr, nullptr,
                   sh_sub, sh_dg, sh_idx, sh_h, sh_c, sh_b2);
    __syncthreads();
  }
  __threadfence();
  grid.sync();

  // P5: round-2 keygen into registers + histogram
  {
    uint32_t sk0, sk1;
    subkey_for_round(b, 1, sk0, sk1);
    sh_h[t] = 0; __syncthreads();
    const int base = chunk * 4096;
#pragma unroll
    for (int e = 0; e < 16; ++e) {
      const int i = base + e * 256 + t;
      uint32_t o0, o1;
      threefry2x32(sk0, sk1, 0u, (uint32_t)i, o0, o1);
      const uint32_t bits = o0 ^ o1;
      v[e] = ((uint64_t)bits << 16) | (uint64_t)i;
      atomicAdd(&sh_h[bits >> 24], 1u);
    }
    __syncthreads();
    if (sh_h[t]) atomicAdd(&hist[b * 256 + t], sh_h[t]);
  }
  grid.sync();

  // P6: prefix round 2
  if (bid < B_SZ) prefix_phase(bid, t, hist, baseArr, cur, sh_c);
  __threadfence();
  grid.sync();

  // P7: scatter round 2 (head buckets only) from registers into CV
  {
    sh_c[t] = 0;
    sh_b2[t] = (baseArr[b * 257 + t] < K_SZ) ? 1u : 0u;
    __syncthreads();
    uint32_t r[16], dgv[16];
#pragma unroll
    for (int e = 0; e < 16; ++e) {
      dgv[e] = (uint32_t)(v[e] >> 40) & 0xFFu;
      r[e] = sh_b2[dgv[e]] ? atomicAdd(&sh_c[dgv[e]], 1u) : 0u;
    }
    __syncthreads();
    if (sh_c[t]) sh_h[t] = atomicAdd(&cur[b * 256 + t], sh_c[t]);
    __syncthreads();
    uint64_t* __restrict__ dst = CV + (size_t)b * N_SZ;
#pragma unroll
    for (int e = 0; e < 16; ++e)
      if (sh_b2[dgv[e]]) dst[sh_h[dgv[e]] + r[e]] = v[e];
  }
  __threadfence();
  grid.sync();

  // P8: finalize head buckets (grid-stride over 32*48, 3/block) -> j-bucket pairs
  for (int vb = bid; vb < B_SZ * 48; vb += NBLK) {
    rank_bucket<1>(vb / 48, vb % 48, t, CV, baseArr, S1v, jcnt, jb,
                   sh_sub, sh_dg, sh_idx, sh_h, sh_c, sh_b2);
    __syncthreads();
  }
  __threadfence();
  grid.sync();

  // P9: compact capped j-buckets into dense bucket-ordered pair list sp
  if (bid < B_SZ) {
    uint32_t c = jcnt[bid * 256 + t];
    if (c > JCAP) c = JCAP;
    sh_h[t] = c; sh_c[t] = c;
    __syncthreads();
    for (int off = 1; off < 256; off <<= 1) {
      const uint32_t y = (t >= off) ? sh_c[t - off] : 0u;
      __syncthreads();
      sh_c[t] += y;
      __syncthreads();
    }
    const uint32_t base = sh_c[t] - sh_h[t];
    const uint32_t* __restrict__ src = jb + ((size_t)bid * 256 + t) * JCAP;
    uint32_t* __restrict__ dst = sp + (size_t)bid * K_SZ + base;
    for (uint32_t i = 0; i < sh_h[t]; ++i) dst[i] = src[i];
  }
}

// gather: one (b,c) row per block. Random LDS writes, coalesced float4 stores.
__global__ __launch_bounds__(256) void gather_staged(const float* __restrict__ x,
                                                     const uint32_t* __restrict__ sp,
                                                     float* __restrict__ y) {
  __shared__ float row[K_SZ];   // 32 KiB
  const int t = threadIdx.x, c = blockIdx.x, b = blockIdx.y;
  const uint32_t* __restrict__ spb = sp + (size_t)b * K_SZ;
  const float* __restrict__ xr = x + ((size_t)b * C_SZ + c) * N_SZ;
#pragma unroll 8
  for (int w = 0; w < 32; ++w) {
    const uint32_t p = spb[w * 256 + t];
    row[p & 0xFFFFu] = xr[p >> 16];
  }
  __syncthreads();
  float4* __restrict__ yr4 = (float4*)(y + ((size_t)b * C_SZ + c) * K_SZ);
  const float4* __restrict__ r4 = (const float4*)row;
#pragma unroll
  for (int w = 0; w < 8; ++w) yr4[w * 256 + t] = r4[w * 256 + t];
}

extern "C" void kernel_launch(void* const* d_in, const int* in_sizes, int n_in,
                              void* d_out, int out_size, void* d_ws, size_t ws_size,
                              hipStream_t stream) {
  (void)in_sizes; (void)n_in; (void)out_size; (void)ws_size;
  const float* x = (const float*)d_in[0];
  float* y = (float*)d_out;

  // d_out (64 MiB) scratch; gather fully overwrites it and reads only x + d_ws.
  char* base = (char*)d_out;
  uint64_t* BV = (uint64_t*)base;                         // 16 MiB round-1 bucketed
  uint64_t* CV = (uint64_t*)(base + (16u << 20));         // 16 MiB round-2 head bucketed
  uint16_t* S1v = (uint16_t*)(base + (32u << 20));        // 4 MiB u16 value table
  uint32_t* hist    = (uint32_t*)(base + (40u << 20));               // 32 KiB
  uint32_t* baseArr = (uint32_t*)(base + (40u << 20) + (64u << 10)); // ~33 KiB
  uint32_t* cur     = (uint32_t*)(base + (40u << 20) + (128u << 10));// 32 KiB
  // d_ws
  uint32_t* jcnt = (uint32_t*)d_ws;                              // 32 KiB
  uint32_t* jb   = (uint32_t*)((char*)d_ws + (64u << 10));       // 2.62 MiB
  uint32_t* sp   = (uint32_t*)((char*)d_ws + (4u << 20));        // 1 MiB

  void* args[] = {&BV, &CV, &S1v, &hist, &baseArr, &cur, &jcnt, &jb, &sp};
  hipLaunchCooperativeKernel((void*)fused_sort, dim3(NBLK), dim3(256), args, 0, stream);
  gather_staged<<<dim3(C_SZ, B_SZ), dim3(256), 0, stream>>>(x, sp, y);
}

// Round 7
// 196.437 us; speedup vs baseline: 4.9604x; 4.9604x over previous
//
#include <hip/hip_runtime.h>
#include <stdint.h>

#define B_SZ 32
#define C_SZ 64
#define N_SZ 65536
#define K_SZ 8192
#define BCAP 384   // fixed per-bucket capacity (Poisson(256), 8 sigma)
#define NHEAD 48   // head buckets for round 2 (verified: base(48) >= K)
#define JCAP 80    // per j-bucket capacity (verified no overflow)

__device__ __forceinline__ uint32_t rotl32(uint32_t v, int r) {
  return (v << r) | (v >> (32 - r));
}

// JAX Threefry-2x32, 20 rounds.
__device__ __forceinline__ void threefry2x32(uint32_t k0, uint32_t k1,
                                             uint32_t x0, uint32_t x1,
                                             uint32_t& o0, uint32_t& o1) {
  const uint32_t ks2 = k0 ^ k1 ^ 0x1BD11BDAu;
  x0 += k0; x1 += k1;
#define TF_R(r) { x0 += x1; x1 = rotl32(x1, (r)); x1 ^= x0; }
  TF_R(13) TF_R(15) TF_R(26) TF_R(6)   x0 += k1;  x1 += ks2 + 1u;
  TF_R(17) TF_R(29) TF_R(16) TF_R(24)  x0 += ks2; x1 += k0  + 2u;
  TF_R(13) TF_R(15) TF_R(26) TF_R(6)   x0 += k0;  x1 += k1  + 3u;
  TF_R(17) TF_R(29) TF_R(16) TF_R(24)  x0 += k1;  x1 += ks2 + 4u;
  TF_R(13) TF_R(15) TF_R(26) TF_R(6)   x0 += ks2; x1 += k0  + 5u;
#undef TF_R
  o0 = x0; o1 = x1;
}

__device__ __forceinline__ void subkey_for_round(int b, int round,
                                                 uint32_t& sk0, uint32_t& sk1) {
  uint32_t c0, c1;
  threefry2x32(0u, 1u, 0u, (uint32_t)b, c0, c1);
  for (int r = 0; r < round; ++r) {
    uint32_t n0, n1;
    threefry2x32(c0, c1, 0u, 0u, n0, n1);
    c0 = n0; c1 = n1;
  }
  threefry2x32(c0, c1, 0u, 1u, sk0, sk1);
}

// zero cnt1 | cnt2 | jcnt (contiguous 96 KiB in d_ws)
__global__ __launch_bounds__(256) void zero_cnt(uint32_t* __restrict__ z) {
  z[blockIdx.x * 256 + threadIdx.x] = 0;
}

// round-1: keygen (recomputed, nothing staged) + direct fixed-cap bucket scatter.
__global__ __launch_bounds__(256) void gen_scatter1(uint64_t* __restrict__ BVfix,
                                                    uint32_t* __restrict__ cnt1) {
  __shared__ uint32_t lcnt[256];
  __shared__ uint32_t gb[256];
  const int t = threadIdx.x, chunk = blockIdx.x, b = blockIdx.y;
  lcnt[t] = 0; __syncthreads();
  uint32_t sk0, sk1;
  subkey_for_round(b, 0, sk0, sk1);
  uint64_t v[16]; uint32_t r[16], dg[16];
  const int base = chunk * 4096;
#pragma unroll
  for (int e = 0; e < 16; ++e) {
    const int i = base + e * 256 + t;
    uint32_t o0, o1;
    threefry2x32(sk0, sk1, 0u, (uint32_t)i, o0, o1);
    const uint32_t bits = o0 ^ o1;
    v[e] = ((uint64_t)bits << 16) | (uint64_t)i;
    dg[e] = bits >> 24;
    r[e] = atomicAdd(&lcnt[dg[e]], 1u);
  }
  __syncthreads();
  if (lcnt[t]) gb[t] = atomicAdd(&cnt1[b * 256 + t], lcnt[t]);
  __syncthreads();
#pragma unroll
  for (int e = 0; e < 16; ++e) {
    const uint32_t slot = gb[dg[e]] + r[e];
    if (slot < BCAP)
      BVfix[((size_t)(b * 256 + dg[e])) * BCAP + slot] = v[e];
  }
}

// per-batch exclusive scan of 256 bucket counts -> baseArr(257).
__global__ __launch_bounds__(256) void prefix1(const uint32_t* __restrict__ cnt1,
                                               uint32_t* __restrict__ baseArr) {
  __shared__ uint32_t sc[256];
  const int b = blockIdx.x, d = threadIdx.x;
  uint32_t h = cnt1[b * 256 + d];
  if (h > BCAP) h = BCAP;
  sc[d] = h; __syncthreads();
  for (int off = 1; off < 256; off <<= 1) {
    const uint32_t y = (d >= off) ? sc[d - off] : 0u;
    __syncthreads();
    sc[d] += y;
    __syncthreads();
  }
  baseArr[b * 257 + d] = sc[d] - h;
  if (d == 255) baseArr[b * 257 + 256] = sc[255];
}

// two-level counting-rank of one bucket: order = (key bits 23..16, key bits
// 15..0, pos) == stable sort by full key. Writes S1v[global rank] = pos.
__global__ __launch_bounds__(256) void rank_sort1(const uint64_t* __restrict__ BVfix,
                                                  const uint32_t* __restrict__ cnt1,
                                                  const uint32_t* __restrict__ baseArr,
                                                  uint16_t* __restrict__ S1v) {
  __shared__ uint32_t sub[BCAP];
  __shared__ uint16_t dg[BCAP];
  __shared__ uint16_t idxt[BCAP];
  __shared__ uint32_t hist[256];
  __shared__ uint32_t sc[256];
  __shared__ uint32_t cur[256];
  __shared__ uint32_t base2[257];
  const int t = threadIdx.x, u = blockIdx.x, b = blockIdx.y;
  uint32_t n = cnt1[b * 256 + u];
  if (n > BCAP) n = BCAP;
  const uint64_t* __restrict__ g = BVfix + ((size_t)(b * 256 + u)) * BCAP;
  const uint32_t base = baseArr[b * 257 + u];

  hist[t] = 0; __syncthreads();
  uint64_t rec[2] = {0, 0};
#pragma unroll
  for (int w = 0; w < 2; ++w) {
    const int e = t + w * 256;
    if (e < (int)n) {
      rec[w] = g[e];
      const uint32_t key = (uint32_t)(rec[w] >> 16);
      const uint32_t d = (key >> 16) & 0xFFu;
      sub[e] = ((key & 0xFFFFu) << 16) | (uint32_t)(rec[w] & 0xFFFFull);
      dg[e] = (uint16_t)d;
      atomicAdd(&hist[d], 1u);
    }
  }
  __syncthreads();
  const uint32_t h = hist[t];
  sc[t] = h; __syncthreads();
  for (int off = 1; off < 256; off <<= 1) {
    const uint32_t y = (t >= off) ? sc[t - off] : 0u;
    __syncthreads();
    sc[t] += y;
    __syncthreads();
  }
  base2[t] = sc[t] - h;
  cur[t] = sc[t] - h;
  if (t == 255) base2[256] = sc[255];
  __syncthreads();
#pragma unroll
  for (int w = 0; w < 2; ++w) {
    const int e = t + w * 256;
    if (e < (int)n) idxt[atomicAdd(&cur[dg[e]], 1u)] = (uint16_t)e;
  }
  __syncthreads();
#pragma unroll
  for (int w = 0; w < 2; ++w) {
    const int e = t + w * 256;
    if (e < (int)n) {
      const uint32_t d = dg[e], s = sub[e];
      const uint32_t lo = base2[d], hi = base2[d + 1];
      uint32_t r = 0;
      for (uint32_t i = lo; i < hi; ++i) r += (sub[idxt[i]] < s) ? 1u : 0u;
      S1v[(size_t)b * N_SZ + base + lo + r] = (uint16_t)(rec[w] & 0xFFFFull);
    }
  }
}

// round-2: keygen + direct scatter of head buckets (u < NHEAD) only.
__global__ __launch_bounds__(256) void gen_scatter2(uint64_t* __restrict__ CVfix,
                                                    uint32_t* __restrict__ cnt2) {
  __shared__ uint32_t lcnt[256];
  __shared__ uint32_t gb[256];
  const int t = threadIdx.x, chunk = blockIdx.x, b = blockIdx.y;
  lcnt[t] = 0; __syncthreads();
  uint32_t sk0, sk1;
  subkey_for_round(b, 1, sk0, sk1);
  uint64_t v[16]; uint32_t r[16], dg[16];
  const int base = chunk * 4096;
#pragma unroll
  for (int e = 0; e < 16; ++e) {
    const int i = base + e * 256 + t;
    uint32_t o0, o1;
    threefry2x32(sk0, sk1, 0u, (uint32_t)i, o0, o1);
    const uint32_t bits = o0 ^ o1;
    v[e] = ((uint64_t)bits << 16) | (uint64_t)i;
    dg[e] = bits >> 24;
    r[e] = (dg[e] < NHEAD) ? atomicAdd(&lcnt[dg[e]], 1u) : 0u;
  }
  __syncthreads();
  if (t < NHEAD && lcnt[t]) gb[t] = atomicAdd(&cnt2[b * 256 + t], lcnt[t]);
  __syncthreads();
#pragma unroll
  for (int e = 0; e < 16; ++e) {
    if (dg[e] < NHEAD) {
      const uint32_t slot = gb[dg[e]] + r[e];
      if (slot < BCAP)
        CVfix[((size_t)(b * NHEAD + dg[e])) * BCAP + slot] = v[e];
    }
  }
}

// per-batch exclusive scan over the NHEAD counted buckets.
__global__ __launch_bounds__(256) void prefix2(const uint32_t* __restrict__ cnt2,
                                               uint32_t* __restrict__ baseArr2) {
  __shared__ uint32_t sc[256];
  const int b = blockIdx.x, d = threadIdx.x;
  uint32_t h = 0;
  if (d < NHEAD) { h = cnt2[b * 256 + d]; if (h > BCAP) h = BCAP; }
  sc[d] = h; __syncthreads();
  for (int off = 1; off < 256; off <<= 1) {
    const uint32_t y = (d >= off) ? sc[d - off] : 0u;
    __syncthreads();
    sc[d] += y;
    __syncthreads();
  }
  if (d < NHEAD) baseArr2[b * NHEAD + d] = sc[d] - h;
}

// rank head buckets of round 2; emit (j<<16)|q pairs into j-buckets (j>>8).
__global__ __launch_bounds__(256) void finalize_rank(const uint64_t* __restrict__ CVfix,
                                                     const uint32_t* __restrict__ cnt2,
                                                     const uint32_t* __restrict__ baseArr2,
                                                     const uint16_t* __restrict__ S1v,
                                                     uint32_t* __restrict__ jcnt,
                                                     uint32_t* __restrict__ jb) {
  __shared__ uint32_t sub[BCAP];
  __shared__ uint16_t dg[BCAP];
  __shared__ uint16_t idxt[BCAP];
  __shared__ uint32_t hist[256];
  __shared__ uint32_t sc[256];
  __shared__ uint32_t cur[256];
  __shared__ uint32_t base2[257];
  const int t = threadIdx.x, u = blockIdx.x, b = blockIdx.y;
  const uint32_t base = baseArr2[b * NHEAD + u];
  if (base >= K_SZ) return;
  uint32_t n = cnt2[b * 256 + u];
  if (n > BCAP) n = BCAP;
  const uint64_t* __restrict__ g = CVfix + ((size_t)(b * NHEAD + u)) * BCAP;

  hist[t] = 0; __syncthreads();
  uint64_t rec[2] = {0, 0};
#pragma unroll
  for (int w = 0; w < 2; ++w) {
    const int e = t + w * 256;
    if (e < (int)n) {
      rec[w] = g[e];
      const uint32_t key = (uint32_t)(rec[w] >> 16);
      const uint32_t d = (key >> 16) & 0xFFu;
      sub[e] = ((key & 0xFFFFu) << 16) | (uint32_t)(rec[w] & 0xFFFFull);
      dg[e] = (uint16_t)d;
      atomicAdd(&hist[d], 1u);
    }
  }
  __syncthreads();
  const uint32_t h = hist[t];
  sc[t] = h; __syncthreads();
  for (int off = 1; off < 256; off <<= 1) {
    const uint32_t y = (t >= off) ? sc[t - off] : 0u;
    __syncthreads();
    sc[t] += y;
    __syncthreads();
  }
  base2[t] = sc[t] - h;
  cur[t] = sc[t] - h;
  if (t == 255) base2[256] = sc[255];
  __syncthreads();
#pragma unroll
  for (int w = 0; w < 2; ++w) {
    const int e = t + w * 256;
    if (e < (int)n) idxt[atomicAdd(&cur[dg[e]], 1u)] = (uint16_t)e;
  }
  __syncthreads();
  const uint16_t* __restrict__ s1 = S1v + (size_t)b * N_SZ;
#pragma unroll
  for (int w = 0; w < 2; ++w) {
    const int e = t + w * 256;
    if (e < (int)n) {
      const uint32_t d = dg[e], s = sub[e];
      const uint32_t lo = base2[d], hi = base2[d + 1];
      uint32_t r = 0;
      for (uint32_t i = lo; i < hi; ++i) r += (sub[idxt[i]] < s) ? 1u : 0u;
      const uint32_t q = base + lo + r;
      if (q < K_SZ) {
        const uint32_t p = (uint32_t)(rec[w] & 0xFFFFull);   // round-1 rank
        const uint32_t j = (uint32_t)s1[p];                  // permutation value
        const uint32_t slot = atomicAdd(&jcnt[b * 256 + (j >> 8)], 1u);
        if (slot < JCAP)
          jb[((size_t)b * 256 + (j >> 8)) * JCAP + slot] = (j << 16) | q;
      }
    }
  }
}

// compact capped j-buckets into dense bucket-ordered pair list sp[b][0..K).
__global__ __launch_bounds__(256) void compact_pairs(const uint32_t* __restrict__ jcnt,
                                                     const uint32_t* __restrict__ jb,
                                                     uint32_t* __restrict__ sp) {
  __shared__ uint32_t sc[256];
  __shared__ uint32_t cnt[256];
  const int b = blockIdx.x, t = threadIdx.x;
  uint32_t c = jcnt[b * 256 + t];
  if (c > JCAP) c = JCAP;
  cnt[t] = c; sc[t] = c;
  __syncthreads();
  for (int off = 1; off < 256; off <<= 1) {
    const uint32_t y = (t >= off) ? sc[t - off] : 0u;
    __syncthreads();
    sc[t] += y;
    __syncthreads();
  }
  const uint32_t base = sc[t] - cnt[t];
  const uint32_t* __restrict__ src = jb + ((size_t)b * 256 + t) * JCAP;
  uint32_t* __restrict__ dst = sp + (size_t)b * K_SZ + base;
  for (uint32_t i = 0; i < cnt[t]; ++i) dst[i] = src[i];
}

// gather: one (b,c) row per block. Random LDS writes, coalesced float4 stores.
__global__ __launch_bounds__(256) void gather_staged(const float* __restrict__ x,
                                                     const uint32_t* __restrict__ sp,
                                                     float* __restrict__ y) {
  __shared__ float row[K_SZ];   // 32 KiB
  const int t = threadIdx.x, c = blockIdx.x, b = blockIdx.y;
  const uint32_t* __restrict__ spb = sp + (size_t)b * K_SZ;
  const float* __restrict__ xr = x + ((size_t)b * C_SZ + c) * N_SZ;
#pragma unroll 8
  for (int w = 0; w < 32; ++w) {
    const uint32_t p = spb[w * 256 + t];
    row[p & 0xFFFFu] = xr[p >> 16];
  }
  __syncthreads();
  float4* __restrict__ yr4 = (float4*)(y + ((size_t)b * C_SZ + c) * K_SZ);
  const float4* __restrict__ r4 = (const float4*)row;
#pragma unroll
  for (int w = 0; w < 8; ++w) yr4[w * 256 + t] = r4[w * 256 + t];
}

extern "C" void kernel_launch(void* const* d_in, const int* in_sizes, int n_in,
                              void* d_out, int out_size, void* d_ws, size_t ws_size,
                              hipStream_t stream) {
  (void)in_sizes; (void)n_in; (void)out_size; (void)ws_size;
  const float* x = (const float*)d_in[0];
  float* y = (float*)d_out;

  // d_out (64 MiB) scratch; gather fully overwrites it and reads only x + d_ws.
  char* base = (char*)d_out;
  uint64_t* BVfix = (uint64_t*)base;                      // 24 MiB fixed-cap round-1 buckets
  uint64_t* CVfix = (uint64_t*)(base + (26u << 20));      // 4.5 MiB fixed-cap round-2 head buckets
  uint16_t* S1v   = (uint16_t*)(base + (31u << 20));      // 4 MiB u16 value table
  uint32_t* baseArr  = (uint32_t*)(base + (36u << 20));   // 33 KiB
  uint32_t* baseArr2 = (uint32_t*)(base + (37u << 20));   // 6 KiB
  // d_ws: [cnt1 32K | cnt2 32K | jcnt 32K | pad | jb | sp]
  uint32_t* cnt1 = (uint32_t*)d_ws;
  uint32_t* cnt2 = (uint32_t*)((char*)d_ws + (32u << 10));
  uint32_t* jcnt = (uint32_t*)((char*)d_ws + (64u << 10));
  uint32_t* jb   = (uint32_t*)((char*)d_ws + (128u << 10));   // 2.62 MiB
  uint32_t* sp   = (uint32_t*)((char*)d_ws + (4u << 20));     // 1 MiB

  const dim3 blk(256);
  const dim3 ggen(16, B_SZ);

  zero_cnt<<<dim3(96), blk, 0, stream>>>(cnt1);   // zeroes cnt1+cnt2+jcnt (96 KiB)
  // round 1
  gen_scatter1<<<ggen, blk, 0, stream>>>(BVfix, cnt1);
  prefix1<<<dim3(B_SZ), blk, 0, stream>>>(cnt1, baseArr);
  rank_sort1<<<dim3(256, B_SZ), blk, 0, stream>>>(BVfix, cnt1, baseArr, S1v);
  // round 2
  gen_scatter2<<<ggen, blk, 0, stream>>>(CVfix, cnt2);
  prefix2<<<dim3(B_SZ), blk, 0, stream>>>(cnt2, baseArr2);
  finalize_rank<<<dim3(NHEAD, B_SZ), blk, 0, stream>>>(CVfix, cnt2, baseArr2, S1v, jcnt, jb);
  compact_pairs<<<dim3(B_SZ), blk, 0, stream>>>(jcnt, jb, sp);
  // gather
  gather_staged<<<dim3(C_SZ, B_SZ), blk, 0, stream>>>(x, sp, y);
}